// Round 5
// baseline (339.621 us; speedup 1.0000x reference)
//
#include <hip/hip_runtime.h>
#include <hip/hip_cooperative_groups.h>

namespace cg = cooperative_groups;

// Problem constants (match reference)
#define C_DIM 16
#define R_DIM 1024
#define T_DIM 4096
#define ROWS_PER_BLOCK 16
#define NBLOCKS (C_DIM * (R_DIM / ROWS_PER_BLOCK))   // 1024 — also the write-phase grid
#define NTHREADS 256

// ws: int32/float slot[C][T] (256 KB). Phases: init(-1) -> atomicMax scatter ->
// resolve slot = rp[m<0?R:m] in-place -> outer-product stream of out[C][R][T].
__global__ __launch_bounds__(NTHREADS) void fused_all(
        const int* __restrict__ rho, const int* __restrict__ theta,
        const int* __restrict__ f, const float* __restrict__ rp,
        const float* __restrict__ r, int* __restrict__ slot,
        float* __restrict__ out, int n)
{
    cg::grid_group grid = cg::this_grid();
    const int tid = blockIdx.x * NTHREADS + threadIdx.x;   // 0..262143

    // Phase 0: init slot = -1 (65536 slots; first 65536 threads)
    if (tid < C_DIM * T_DIM) slot[tid] = -1;
    grid.sync();

    // Phase 1: scatter atomicMax, grid-stride (<=2 points/thread)
    for (int i = tid; i < n; i += NBLOCKS * NTHREADS) {
        atomicMax(&slot[f[i] * T_DIM + theta[i]], rho[i]);
    }
    grid.sync();

    // Phase 2: resolve slot -> rp value, in place (65536 gathers total)
    if (tid < C_DIM * T_DIM) {
        int m = slot[tid];
        reinterpret_cast<float*>(slot)[tid] = rp[m < 0 ? R_DIM : m];
    }
    grid.sync();

    // Phase 3: outer-product stream. Block = (c, 16-row chunk), exactly NBLOCKS.
    const float* val = reinterpret_cast<const float*>(slot);
    const int c   = blockIdx.x >> 6;                 // / (R/ROWS_PER_BLOCK)
    const int rr0 = (blockIdx.x & 63) * ROWS_PER_BLOCK;

    const float4* vrow = reinterpret_cast<const float4*>(val + c * T_DIM);
    float4 v[4];
#pragma unroll
    for (int k = 0; k < 4; ++k) v[k] = vrow[threadIdx.x + k * 256];

    float* obase = out + ((size_t)c * R_DIM + rr0) * T_DIM;
    for (int j = 0; j < ROWS_PER_BLOCK; ++j) {
        float rv = r[rr0 + j];                       // wave-uniform scalar load
        float4* orow = reinterpret_cast<float4*>(obase + (size_t)j * T_DIM);
#pragma unroll
        for (int k = 0; k < 4; ++k) {
            float4 o = { v[k].x - rv, v[k].y - rv, v[k].z - rv, v[k].w - rv };
            orow[threadIdx.x + k * 256] = o;
        }
    }
}

extern "C" void kernel_launch(void* const* d_in, const int* in_sizes, int n_in,
                              void* d_out, int out_size, void* d_ws, size_t ws_size,
                              hipStream_t stream) {
    const int*   rho   = (const int*)d_in[0];
    const int*   theta = (const int*)d_in[1];
    const int*   f     = (const int*)d_in[2];
    const float* rp    = (const float*)d_in[3];
    const float* r     = (const float*)d_in[4];
    float* out = (float*)d_out;
    int* slot = (int*)d_ws;                          // 256 KB
    int n = in_sizes[0];

    void* args[] = { (void*)&rho, (void*)&theta, (void*)&f, (void*)&rp,
                     (void*)&r, (void*)&slot, (void*)&out, (void*)&n };
    hipLaunchCooperativeKernel((const void*)fused_all,
                               dim3(NBLOCKS), dim3(NTHREADS),
                               args, 0, stream);
}

// Round 6
// 74.212 us; speedup vs baseline: 4.5764x; 4.5764x over previous
//
#include <hip/hip_runtime.h>

// Problem constants (match reference)
#define C_DIM 16
#define R_DIM 1024
#define T_DIM 4096

typedef float f32x4 __attribute__((ext_vector_type(4)));

// ws: int32 maxrho[C][T] (256 KB). memset(0xFF) -> scatter -> fused resolve+write.

// 4 points per thread via int4 loads; tiny scalar tail in thread 0.
__global__ void scatter_max4(const int4* __restrict__ rho4,
                             const int4* __restrict__ theta4,
                             const int4* __restrict__ f4,
                             const int* __restrict__ rho,
                             const int* __restrict__ theta,
                             const int* __restrict__ f,
                             int* __restrict__ maxrho, int n) {
    int n4 = n >> 2;
    int i = blockIdx.x * blockDim.x + threadIdx.x;
    if (i < n4) {
        int4 rh = rho4[i], th = theta4[i], ff = f4[i];
        atomicMax(&maxrho[ff.x * T_DIM + th.x], rh.x);
        atomicMax(&maxrho[ff.y * T_DIM + th.y], rh.y);
        atomicMax(&maxrho[ff.z * T_DIM + th.z], rh.z);
        atomicMax(&maxrho[ff.w * T_DIM + th.w], rh.w);
    }
    if (i == 0) {
        for (int k = n4 << 2; k < n; ++k)
            atomicMax(&maxrho[f[k] * T_DIM + theta[k]], rho[k]);
    }
}

// Block = (c, t-chunk of 1024 floats, rr-chunk of 128 rows): 16*4*8 = 512 blocks.
// Prologue: each thread resolves ITS OWN float4 of val (no cross-block redundancy
// beyond the 8 rr-chunks sharing a t-slice). Hot loop: 128 rows x 1 nt float4 store.
__global__ __launch_bounds__(256) void resolve_write(
        const int* __restrict__ maxrho,
        const float* __restrict__ rp,
        const float* __restrict__ r,
        float* __restrict__ out) {
    const int c   = blockIdx.x >> 5;            // 512 blocks -> c = 0..15
    const int t0  = ((blockIdx.x >> 3) & 3) * 1024;
    const int rr0 = (blockIdx.x & 7) * 128;

    // Resolve this thread's 4 t-columns once.
    const int4 m = *reinterpret_cast<const int4*>(
        maxrho + c * T_DIM + t0 + 4 * threadIdx.x);
    f32x4 v;
    v.x = rp[m.x < 0 ? R_DIM : m.x];
    v.y = rp[m.y < 0 ? R_DIM : m.y];
    v.z = rp[m.z < 0 ? R_DIM : m.z];
    v.w = rp[m.w < 0 ? R_DIM : m.w];

    float* base = out + ((size_t)(c * R_DIM + rr0)) * T_DIM + t0 + 4 * threadIdx.x;

#pragma unroll 4
    for (int j = 0; j < 128; ++j) {
        float rv = r[rr0 + j];                  // wave-uniform scalar load (L1)
        f32x4 o = v - rv;
        __builtin_nontemporal_store(o, reinterpret_cast<f32x4*>(base + (size_t)j * T_DIM));
    }
}

extern "C" void kernel_launch(void* const* d_in, const int* in_sizes, int n_in,
                              void* d_out, int out_size, void* d_ws, size_t ws_size,
                              hipStream_t stream) {
    const int*   rho   = (const int*)d_in[0];
    const int*   theta = (const int*)d_in[1];
    const int*   f     = (const int*)d_in[2];
    const float* rp    = (const float*)d_in[3];
    const float* r     = (const float*)d_in[4];
    float* out = (float*)d_out;

    int* maxrho = (int*)d_ws;                   // 256 KB
    const int n = in_sizes[0];

    // 1. maxrho = -1 (0xFF bytes)
    hipMemsetAsync(maxrho, 0xFF, (size_t)C_DIM * T_DIM * sizeof(int), stream);

    // 2. vectorized scatter atomicMax (4 pts/thread)
    {
        int n4 = n >> 2;
        int blocks = (n4 + 255) / 256;
        scatter_max4<<<blocks, 256, 0, stream>>>(
            (const int4*)rho, (const int4*)theta, (const int4*)f,
            rho, theta, f, maxrho, n);
    }

    // 3. fused resolve + streamed output: 512 blocks (2/CU), nt float4 stores
    resolve_write<<<512, 256, 0, stream>>>(maxrho, rp, r, out);
}

// Round 7
// 73.788 us; speedup vs baseline: 4.6027x; 1.0057x over previous
//
#include <hip/hip_runtime.h>

// Problem constants (match reference)
#define C_DIM 16
#define R_DIM 1024
#define T_DIM 4096
#define TABLE (C_DIM * T_DIM)     // 65536 slots
#define REP 8                     // scatter-table replicas (contention fix)

typedef float f32x4 __attribute__((ext_vector_type(4)));

// ws: int32 maxrho[rep][C][T] (rep*256 KB). memset(0xFF) -> replicated scatter
// -> fused {replica-max + rp-resolve + outer-product stream}.

__global__ void scatter_max2(const int2* __restrict__ rho2,
                             const int2* __restrict__ theta2,
                             const int2* __restrict__ f2,
                             const int* __restrict__ rho,
                             const int* __restrict__ theta,
                             const int* __restrict__ f,
                             int* __restrict__ maxrho,
                             int rep_mask, int n) {
    int* table = maxrho + (blockIdx.x & rep_mask) * TABLE;
    int n2 = n >> 1;
    int i = blockIdx.x * blockDim.x + threadIdx.x;
    if (i < n2) {
        int2 rh = rho2[i], th = theta2[i], ff = f2[i];
        atomicMax(&table[ff.x * T_DIM + th.x], rh.x);
        atomicMax(&table[ff.y * T_DIM + th.y], rh.y);
    }
    if (i == 0 && (n & 1)) {
        int k = n - 1;
        atomicMax(&table[f[k] * T_DIM + theta[k]], rho[k]);
    }
}

// Block = (c, t-chunk of 1024, rr-chunk of 128 rows): 16*4*8 = 512 blocks.
// Prologue: max over replicas, then resolve this thread's 4 t-columns via rp.
// Hot loop: 128 rows x 1 plain float4 store per thread.
__global__ __launch_bounds__(256) void resolve_write(
        const int* __restrict__ maxrho, int rep,
        const float* __restrict__ rp,
        const float* __restrict__ r,
        float* __restrict__ out) {
    const int c   = blockIdx.x >> 5;
    const int t0  = ((blockIdx.x >> 3) & 3) * 1024;
    const int rr0 = (blockIdx.x & 7) * 128;
    const int off = c * T_DIM + t0 + 4 * threadIdx.x;

    int4 m = *reinterpret_cast<const int4*>(maxrho + off);
    for (int q = 1; q < rep; ++q) {
        int4 mq = *reinterpret_cast<const int4*>(maxrho + q * TABLE + off);
        m.x = max(m.x, mq.x); m.y = max(m.y, mq.y);
        m.z = max(m.z, mq.z); m.w = max(m.w, mq.w);
    }

    f32x4 v;
    v.x = rp[m.x < 0 ? R_DIM : m.x];
    v.y = rp[m.y < 0 ? R_DIM : m.y];
    v.z = rp[m.z < 0 ? R_DIM : m.z];
    v.w = rp[m.w < 0 ? R_DIM : m.w];

    float* base = out + ((size_t)(c * R_DIM + rr0)) * T_DIM + t0 + 4 * threadIdx.x;

#pragma unroll 4
    for (int j = 0; j < 128; ++j) {
        float rv = r[rr0 + j];                  // wave-uniform scalar load
        f32x4 o = v - rv;
        *reinterpret_cast<f32x4*>(base + (size_t)j * T_DIM) = o;
    }
}

extern "C" void kernel_launch(void* const* d_in, const int* in_sizes, int n_in,
                              void* d_out, int out_size, void* d_ws, size_t ws_size,
                              hipStream_t stream) {
    const int*   rho   = (const int*)d_in[0];
    const int*   theta = (const int*)d_in[1];
    const int*   f     = (const int*)d_in[2];
    const float* rp    = (const float*)d_in[3];
    const float* r     = (const float*)d_in[4];
    float* out = (float*)d_out;

    int* maxrho = (int*)d_ws;
    const int n = in_sizes[0];

    // Fall back to 1 replica if ws is unexpectedly small.
    const int rep = (ws_size >= (size_t)REP * TABLE * sizeof(int)) ? REP : 1;

    // 1. maxrho[rep] = -1 (0xFF bytes)
    hipMemsetAsync(maxrho, 0xFF, (size_t)rep * TABLE * sizeof(int), stream);

    // 2. replicated scatter atomicMax (2 pts/thread, replica = blockIdx & (rep-1))
    {
        int n2 = n >> 1;
        int blocks = (n2 + 255) / 256;
        scatter_max2<<<blocks, 256, 0, stream>>>(
            (const int2*)rho, (const int2*)theta, (const int2*)f,
            rho, theta, f, maxrho, rep - 1, n);
    }

    // 3. fused replica-max + resolve + streamed output: 512 blocks
    resolve_write<<<512, 256, 0, stream>>>(maxrho, rep, rp, r, out);
}